// Round 10
// baseline (127.163 us; speedup 1.0000x reference)
//
#include <hip/hip_runtime.h>

// Attention, 20 slices of [N=1024, D=256]. R14 (resubmit; prior run died to
// container infra, not the kernel): fuse the two co-resident 256-thr blocks
// into ONE 512-thr block (8 waves, 64 q-rows) so the wave pair (wv, wv+4) --
// which issues IDENTICAL af/vf loads (same m-slice wv&3, same d-quarter) --
// shares them through L1. Surviving model after R8-R13 nulls: per-CU VMEM
// line service is the wall, and the old XCD swizzle put co-resident blocks
// ~2.5 slices apart (disjoint 1MB streams, L1 thrash). Fresh bytes/CU/kt
// halve 64->32KB with guaranteed temporal locality. Everything else is
// R12's verified dataflow: af/vf global->reg (compiler-counted scoreboard
// waits), P through dbuf LDS, ONE lgkm-only barrier per kt, af(kt+1) issued
// right after S(kt), vf(kt+1) inside PV(kt). launch_bounds(512,2): 2
// waves/SIMD, reg cap 256, ~190 demand, no spill.

typedef __attribute__((ext_vector_type(8))) short bf16x8;
typedef __attribute__((ext_vector_type(4))) float f32x4;
typedef __attribute__((ext_vector_type(16))) float f32x16;

// LDS-only barrier: no vmcnt drain (global loads stay in flight)
#define LDS_BARRIER() __asm__ volatile("s_waitcnt lgkmcnt(0)\ns_barrier" ::: "memory")

__device__ __forceinline__ unsigned int pack_bf16_rne(float a, float b) {
    unsigned int ua = __float_as_uint(a); ua += 0x7FFFu + ((ua >> 16) & 1u);
    unsigned int ub = __float_as_uint(b); ub += 0x7FFFu + ((ub >> 16) & 1u);
    return (ua >> 16) | (ub & 0xFFFF0000u);
}
__device__ __forceinline__ unsigned int pack2_trunc(float lo, float hi) {
    return __builtin_amdgcn_perm(__float_as_uint(hi), __float_as_uint(lo), 0x07060302u);
}

// Fused prep (unchanged): bid<640 -> XV tiles, else -> XT tiles.
// XT[slice][n][chunk^(n&7)] bf16.  XV[slice][cc=m>>3][d][j=m&7] bf16.
__global__ __launch_bounds__(256) void prep_kernel(const float* __restrict__ x,
                                                   unsigned short* __restrict__ XT,
                                                   unsigned short* __restrict__ XV) {
    __shared__ __align__(16) unsigned char smem[16384];
    int bid = blockIdx.x;
    int t = threadIdx.x;
    if (bid < 640) {
        uint4* T = (uint4*)smem;                      // [32cc][32d'] 16KB
        int slice = bid >> 5, w = bid & 31;
        int cc0 = (w & 3) * 32, d0 = (w >> 2) * 32;
        const float* xs = x + slice * 262144;
        int ccl = t & 31, dr = t >> 5;
        #pragma unroll
        for (int p = 0; p < 4; ++p) {
            int dl = p * 8 + dr;
            const float* src = xs + (d0 + dl) * 1024 + (cc0 + ccl) * 8;
            float4 a = *(const float4*)(src);
            float4 b = *(const float4*)(src + 4);
            uint4 o;
            o.x = pack_bf16_rne(a.x, a.y); o.y = pack_bf16_rne(a.z, a.w);
            o.z = pack_bf16_rne(b.x, b.y); o.w = pack_bf16_rne(b.z, b.w);
            T[ccl * 32 + (dl ^ ccl)] = o;
        }
        __syncthreads();
        unsigned short* xv = XV + slice * 262144;
        int dl2 = t & 31, cr = t >> 5;
        #pragma unroll
        for (int p = 0; p < 4; ++p) {
            int ccl2 = p * 8 + cr;
            uint4 o = T[ccl2 * 32 + (dl2 ^ ccl2)];
            *(uint4*)(xv + ((cc0 + ccl2) * 256 + d0 + dl2) * 8) = o;
        }
    } else {
        unsigned long long* TX = (unsigned long long*)smem;   // [64n][32dq] 16KB
        int b = bid - 640;
        int slice = b >> 5, w = b & 31;
        int d0 = (w & 1) * 128, n0 = (w >> 1) * 64;
        const float* xs = x + slice * 262144;
        int nq = t & 15, dqh = t >> 4;
        #pragma unroll
        for (int p = 0; p < 2; ++p) {
            int dq = p * 16 + dqh;
            const float* src = xs + (d0 + dq * 4) * 1024 + n0 + nq * 4;
            float4 r0 = *(const float4*)(src);
            float4 r1 = *(const float4*)(src + 1024);
            float4 r2 = *(const float4*)(src + 2048);
            float4 r3 = *(const float4*)(src + 3072);
            const float* f0 = (const float*)&r0; const float* f1 = (const float*)&r1;
            const float* f2 = (const float*)&r2; const float* f3 = (const float*)&r3;
            #pragma unroll
            for (int j = 0; j < 4; ++j) {
                int nl2 = nq * 4 + j;
                unsigned long long q = (unsigned long long)pack_bf16_rne(f0[j], f1[j])
                    | ((unsigned long long)pack_bf16_rne(f2[j], f3[j]) << 32);
                TX[nl2 * 32 + (dq ^ (nl2 & 31))] = q;
            }
        }
        __syncthreads();
        unsigned short* xt = XT + slice * 262144;
        int ch = t & 15, nr = t >> 4;
        #pragma unroll
        for (int p = 0; p < 4; ++p) {
            int nl2 = p * 16 + nr;
            unsigned long long qlo = TX[nl2 * 32 + ((ch * 2) ^ (nl2 & 31))];
            unsigned long long qhi = TX[nl2 * 32 + ((ch * 2 + 1) ^ (nl2 & 31))];
            uint4 o = make_uint4((unsigned int)qlo, (unsigned int)(qlo >> 32),
                                 (unsigned int)qhi, (unsigned int)(qhi >> 32));
            *(uint4*)(xt + (n0 + nl2) * 256 + ((((d0 >> 3) + ch) ^ (nl2 & 7)) * 8)) = o;
        }
    }
}

__global__ __launch_bounds__(512, 2) void attn_kernel(const unsigned short* __restrict__ XT,
                                                      const unsigned short* __restrict__ XV,
                                                      const int* __restrict__ beta,
                                                      float* __restrict__ out) {
    __shared__ __align__(16) unsigned short Pb[2][2][32 * 64]; // [buf][n-half], 16KB
    __shared__ float Lpart[2 * 4 * 32];
    __shared__ __align__(16) float Ltot[64];

    int bid = blockIdx.x;
    int t = ((bid & 7) * 40) + (bid >> 3);      // XCD swizzle (320 blocks)
    int slice = t >> 4, qh = t & 15;            // qh: 64-row q-tile

    int tid = threadIdx.x;
    int lane = tid & 63, wv = tid >> 6;         // 8 waves
    int ms = wv & 3, h = wv >> 2;               // m-slice, n-half (pair (ms,h))
    int nl = lane & 15, g = lane >> 4;          // 16x16 frame
    int lo = lane & 31, hi = lane >> 5;         // 32x32 frame

    const unsigned short* xt_s = XT + slice * 262144;
    const unsigned short* xv_s = XV + slice * 262144;
    float cscale = (float)(beta[0]) * 1.44269504089f;   // beta * log2(e)

    // K-fragment base: row (ms*16+nl) -- wave pair (ms,0),(ms,1) loads the
    // SAME af lines (L1 twin-hit). chunk XOR uses nl&7 (row%8 = nl%8).
    const unsigned short* kb = xt_s + (ms * 16 + nl) * 256;
    bf16x8 af[8];

    // ---- issue af(0) FIRST (longest flight: covers Q-norm prologue) ----
    #pragma unroll
    for (int ks = 0; ks < 8; ++ks)
        af[ks] = *(const bf16x8*)(kb + (((ks * 4 + g) ^ (nl & 7)) * 8));

    // ---- Q fragments: own half's 2 strips of 16 n + fixed softmax max ----
    bf16x8 qf[2][8];
    float mcol[2];
    #pragma unroll
    for (int nq = 0; nq < 2; ++nq) {
        int n = qh * 64 + h * 32 + nq * 16 + nl;
        const unsigned short* qrow = xt_s + n * 256;
        float dg = 0.f;
        #pragma unroll
        for (int ks = 0; ks < 8; ++ks) {
            qf[nq][ks] = *(const bf16x8*)(qrow + (((ks * 4 + g) ^ (n & 7)) * 8));
            const unsigned int* qu = (const unsigned int*)&qf[nq][ks];
            #pragma unroll
            for (int w = 0; w < 4; ++w) {
                float flo = __uint_as_float(qu[w] << 16);
                float fhi = __uint_as_float(qu[w] & 0xFFFF0000u);
                dg = fmaf(flo, flo, dg);
                dg = fmaf(fhi, fhi, dg);
            }
        }
        dg += __shfl_xor(dg, 16);
        dg += __shfl_xor(dg, 32);
        mcol[nq] = dg * cscale;
    }

    f32x16 acc[2];                   // O[own 32n x 64d]: d in [ms*64,+64)
    acc[0] = (f32x16)(0.f); acc[1] = (f32x16)(0.f);
    float lac0 = 0.f, lac1 = 0.f;

    // vf: d-quarter ms -- pair (ms,0),(ms,1) loads the SAME lines.
    const unsigned short* vb = xv_s + (hi * 256 + ms * 64 + lo) * 8;
    bf16x8 vf[8];
    #pragma unroll
    for (int ks = 0; ks < 4; ++ks) {
        vf[ks * 2]     = *(const bf16x8*)(vb + ks * 4096);
        vf[ks * 2 + 1] = *(const bf16x8*)(vb + ks * 4096 + 256);
    }

    for (int kt = 0; kt < 16; ++kt) {
        // ---- S(kt): own 16m x own 32n (compiler-counted af waits) ----
        f32x4 s0 = {0.f,0.f,0.f,0.f}, s1 = {0.f,0.f,0.f,0.f};
        #pragma unroll
        for (int ks = 0; ks < 8; ++ks) {
            s0 = __builtin_amdgcn_mfma_f32_16x16x32_bf16(af[ks], qf[0][ks], s0, 0, 0, 0);
            s1 = __builtin_amdgcn_mfma_f32_16x16x32_bf16(af[ks], qf[1][ks], s1, 0, 0, 0);
        }

        // ---- issue af(kt+1): flight = softmax + barrier + PV ----
        if (kt < 15) {
            const unsigned short* kkt = kb + (kt + 1) * 16384;
            #pragma unroll
            for (int ks = 0; ks < 8; ++ks)
                af[ks] = *(const bf16x8*)(kkt + (((ks * 4 + g) ^ (nl & 7)) * 8));
        }

        // ---- softmax (fixed max) + P write -> Pb[kt&1][h] ----
        {
            float p0 = exp2f(fmaf(s0[0], cscale, -mcol[0]));
            float p1 = exp2f(fmaf(s0[1], cscale, -mcol[0]));
            float p2 = exp2f(fmaf(s0[2], cscale, -mcol[0]));
            float p3 = exp2f(fmaf(s0[3], cscale, -mcol[0]));
            lac0 += (p0 + p1) + (p2 + p3);
            *(uint2*)(&Pb[kt & 1][h][nl * 64 + (((ms * 2 + (g >> 1)) ^ (nl & 7)) * 8) + (g & 1) * 4]) =
                make_uint2(pack2_trunc(p0, p1), pack2_trunc(p2, p3));
        }
        {
            float p0 = exp2f(fmaf(s1[0], cscale, -mcol[1]));
            float p1 = exp2f(fmaf(s1[1], cscale, -mcol[1]));
            float p2 = exp2f(fmaf(s1[2], cscale, -mcol[1]));
            float p3 = exp2f(fmaf(s1[3], cscale, -mcol[1]));
            lac1 += (p0 + p1) + (p2 + p3);
            *(uint2*)(&Pb[kt & 1][h][(16 + nl) * 64 + (((ms * 2 + (g >> 1)) ^ (nl & 7)) * 8) + (g & 1) * 4]) =
                make_uint2(pack2_trunc(p0, p1), pack2_trunc(p2, p3));
        }

        LDS_BARRIER();               // the ONLY barrier per kt: P(kt) visible

        // ---- PV(kt): O[own 32n x 64d] += P * V; vf regs; reload vf(kt+1) ----
        {
            const unsigned short* vnext = vb + (kt + 1) * 16384;
            #pragma unroll
            for (int ks = 0; ks < 4; ++ks) {
                bf16x8 pf = *(const bf16x8*)(&Pb[kt & 1][h][lo * 64 + (((ks * 2 + hi) ^ (lo & 7)) * 8)]);
                acc[0] = __builtin_amdgcn_mfma_f32_32x32x16_bf16(pf, vf[ks * 2],     acc[0], 0, 0, 0);
                acc[1] = __builtin_amdgcn_mfma_f32_32x32x16_bf16(pf, vf[ks * 2 + 1], acc[1], 0, 0, 0);
                if (kt < 15) {
                    vf[ks * 2]     = *(const bf16x8*)(vnext + ks * 4096);
                    vf[ks * 2 + 1] = *(const bf16x8*)(vnext + ks * 4096 + 256);
                }
            }
        }
    }

    // ---- epilogue: softmax denominators, scale, store ----
    lac0 += __shfl_xor(lac0, 16); lac0 += __shfl_xor(lac0, 32);
    lac1 += __shfl_xor(lac1, 16); lac1 += __shfl_xor(lac1, 32);
    if (lane < 16) {
        Lpart[h * 128 + ms * 32 + nl] = lac0;
        Lpart[h * 128 + ms * 32 + 16 + nl] = lac1;
    }
    LDS_BARRIER();
    if (tid < 64) {
        int hh = tid >> 5, r = tid & 31;
        Ltot[tid] = 1.f / (Lpart[hh * 128 + r] + Lpart[hh * 128 + 32 + r] +
                           Lpart[hh * 128 + 64 + r] + Lpart[hh * 128 + 96 + r]);
    }
    LDS_BARRIER();

    float* outs = out + slice * 262144 + (qh * 64 + h * 32) * 256;
    #pragma unroll
    for (int rq = 0; rq < 4; ++rq) {
        f32x4 li = *(const f32x4*)(&Ltot[h * 32 + rq * 8 + hi * 4]);
        #pragma unroll
        for (int j = 0; j < 4; ++j) {
            int nloc = rq * 8 + hi * 4 + j;
            #pragma unroll
            for (int db = 0; db < 2; ++db)
                outs[nloc * 256 + ms * 64 + db * 32 + lo] = acc[db][rq * 4 + j] * li[j];
        }
    }
}

extern "C" void kernel_launch(void* const* d_in, const int* in_sizes, int n_in,
                              void* d_out, int out_size, void* d_ws, size_t ws_size,
                              hipStream_t stream) {
    const float* x = (const float*)d_in[0];
    const int* beta = (const int*)d_in[1];
    float* out = (float*)d_out;
    unsigned short* XT = (unsigned short*)d_ws;                 // 10,485,760 B
    unsigned short* XV = (unsigned short*)d_ws + 5242880;       // 10,485,760 B
    prep_kernel<<<1280, 256, 0, stream>>>(x, XT, XV);
    attn_kernel<<<320, 512, 0, stream>>>(XT, XV, beta, out);
}